// Round 2
// baseline (236.898 us; speedup 1.0000x reference)
//
#include <hip/hip_runtime.h>

// RPN forward on gfx950. R12: k_conv_gemm = true 8-phase template (m201 port).
// R11 post-mortem: coarse 2-barrier dbuf at 1 block/CU lost inter-block overlap
// (MfmaUtil 47.5->38, m196's predicted failure mode). R12 uses per-sub-phase
// {ds_read subtile -> stage 1 half-tile -> counted vmcnt -> bar -> 16 MFMA -> bar}
// with K-split half-tiles (A/B split into 32-ch halves so phase read-sets are
// phase-dependent), mhalf-alternating quadrants, vmcnt(8) twice/tile (never 0
// mid-loop), setprio around MFMA. Accumulation order bit-identical to R10.
// k_prep / k_heads unchanged.

typedef __bf16 bf16x8 __attribute__((ext_vector_type(8)));
typedef float floatx4 __attribute__((ext_vector_type(4)));

#define NB 4
#define NC 2048
#define NH 32
#define NW 32
#define NHID 512
#define NA 9
#define NG 20
#define NANC 9216
#define NM 4096

// workspace layout (bytes)
#define OFF_XH    0ull            // [4][34][34][2048] bf16 (zero halo) = 18939904
#define OFF_WT    18939904ull     // [9][512][2048]    bf16 = 18874368
#define OFF_WH    37814272ull     // [48][512]         bf16
#define OFF_HB    37863424ull     // [48] f32 (pad 256)
#define OFF_MAXG  37863680ull     // [4][20] uint (pad 512)
#define OFF_SUMS  37864192ull     // [2] f32 (pad 128)
#define OFF_CTR   37864320ull     // [1] uint (pad 128)
#define OFF_HIDP  37864448ull     // [nsplit][4096][512] bf16, 4194304 each

// k_prep block ranges
#define PREP_TX   4096
#define PREP_W    1024            // 512 o * 2 halves, LDS-staged
#define PREP_WH   96
#define PREP_HALO 528
#define PREP_MAXG 80
#define PREP_NBLK (PREP_TX + PREP_W + PREP_WH + PREP_HALO + PREP_MAXG + 1)

__device__ __forceinline__ unsigned short f2bf(float f) {
  unsigned int u = __float_as_uint(f);
  u = (u + 0x7fffu + ((u >> 16) & 1u)) >> 16;   // RNE
  return (unsigned short)u;
}

__device__ __forceinline__ void gload16(const void* g, void* l) {
  __builtin_amdgcn_global_load_lds(
      (const __attribute__((address_space(1))) unsigned int*)g,
      (__attribute__((address_space(3))) unsigned int*)l, 16, 0, 0);
}

#define VMCNT(n) asm volatile("s_waitcnt vmcnt(" #n ")" ::: "memory")

__constant__ float c_aw[9] = {2.f,2.f,2.f,4.f,4.f,4.f,6.f,6.f,6.f};
__constant__ float c_ah[9] = {1.f,2.f,3.f,2.f,4.f,6.f,3.f,6.f,9.f};
// tap displacement in xh elements: ((g/3-1)*34 + (g%3-1)) * 2048
__constant__ int c_dsp[9] = {-71680, -69632, -67584, -2048, 0, 2048, 67584, 69632, 71680};

// ---- strict-f32 anchor/IoU helpers (bit-identical in prep-maxg + assign) ----
struct Anc { float x1, y1, x2, y2, areaA; };
__device__ __forceinline__ Anc anc_of(int n) {
  const int a = n % 9, pix = n / 9;
  const int xi = pix & 31, yi = pix >> 5;
  const float hw = c_aw[a]*0.5f, hh = c_ah[a]*0.5f;
  const float xc = xi + 0.5f, yc = yi + 0.5f;
  Anc A;
  A.x1 = fminf(fmaxf(xc - hw, 0.f), 32.f);
  A.y1 = fminf(fmaxf(yc - hh, 0.f), 32.f);
  A.x2 = fminf(fmaxf(xc + hw, 0.f), 32.f);
  A.y2 = fminf(fmaxf(yc + hh, 0.f), 32.f);
  A.areaA = __fmul_rn(__fsub_rn(A.x2, A.x1), __fsub_rn(A.y2, A.y1));
  return A;
}
__device__ __forceinline__ float iou_one(const Anc& A, float4 gp) {
  const float gx1 = gp.x * 0.03125f, gy1 = gp.y * 0.03125f;   // /32 exact
  const float gx2 = gp.z * 0.03125f, gy2 = gp.w * 0.03125f;
  const float dx = fmaxf(__fsub_rn(fminf(A.x2, gx2), fmaxf(A.x1, gx1)), 0.f);
  const float dy = fmaxf(__fsub_rn(fminf(A.y2, gy2), fmaxf(A.y1, gy1)), 0.f);
  const float inter = __fmul_rn(dx, dy);
  const float areaG = __fmul_rn(__fsub_rn(gx2, gx1), __fsub_rn(gy2, gy1));
  const float den = __fadd_rn(__fsub_rn(__fadd_rn(A.areaA, areaG), inter), 1e-8f);
  return __fdiv_rn(inter, den);
}

// ---------------- fused prep ----------------
__global__ __launch_bounds__(256) void k_prep(const float* __restrict__ x,
                                              const float* __restrict__ w1,
                                              const float* __restrict__ cw, const float* __restrict__ cb,
                                              const float* __restrict__ rw, const float* __restrict__ rb,
                                              const float* __restrict__ gtb,
                                              unsigned short* __restrict__ xh,
                                              unsigned short* __restrict__ wt,
                                              unsigned short* __restrict__ wh, float* __restrict__ hb,
                                              unsigned int* __restrict__ maxg,
                                              float* __restrict__ sums, unsigned int* __restrict__ ctr) {
  __shared__ float tile[64][33];
  __shared__ unsigned short wlds[9*1024];
  __shared__ float red[4];
  const int bid = blockIdx.x;
  const int tid = threadIdx.x;

  if (bid < PREP_TX) {                       // ---- x: NCHW f32 -> halo NHWC bf16
    const int c0 = (bid & 31) << 6;
    const int h  = (bid >> 5) & 31;
    const int b  = bid >> 10;
    const int w = tid & 31, cl = tid >> 5;
    const float* src = x + (((size_t)b*NC + c0)*NH + h)*NW;
#pragma unroll
    for (int j = 0; j < 8; ++j) {
      const int c = cl + j*8;
      tile[c][w] = src[(size_t)c*NH*NW + w];
    }
    __syncthreads();
    unsigned short* dst = xh + ((size_t)(b*34 + h + 1)*34 + 1)*2048 + c0;
    const int w2 = tid >> 3, c8 = (tid & 7) << 3;   // 16B store per lane
    unsigned int pk[4];
#pragma unroll
    for (int k = 0; k < 4; ++k) {
      const unsigned int lo = f2bf(tile[c8 + 2*k][w2]);
      const unsigned int hi = f2bf(tile[c8 + 2*k + 1][w2]);
      pk[k] = lo | (hi << 16);
    }
    *(uint4*)(dst + (size_t)w2*2048 + c8) = make_uint4(pk[0], pk[1], pk[2], pk[3]);
    return;
  }
  if (bid < PREP_TX + PREP_W) {              // ---- w1 -> [g][O][C] bf16, LDS-staged
    const int p = bid - PREP_TX;
    const int o = p >> 1, half = p & 1;
    const int c_base = half << 10;
    const float* src = w1 + ((size_t)(o*2048 + c_base))*9;   // 9216 contiguous floats
#pragma unroll
    for (int j = 0; j < 9; ++j) {            // read float4, scatter bf16 into [g][c] LDS
      const int f0 = (j*256 + tid)*4;
      const float4 v = *(const float4*)(src + f0);
      const float vv[4] = {v.x, v.y, v.z, v.w};
#pragma unroll
      for (int e = 0; e < 4; ++e) {
        const int f = f0 + e;
        const int c = f/9, g = f - c*9;
        wlds[g*1024 + c] = f2bf(vv[e]);
      }
    }
    __syncthreads();
#pragma unroll
    for (int j = 0; j < 5; ++j) {            // 1152 uint4 writes (9 g * 128)
      const int idx = j*256 + tid;
      if (idx < 1152) {
        const int g = idx >> 7, off = (idx & 127) << 3;
        *(uint4*)(wt + (size_t)g*NHID*NC + o*2048 + c_base + off) =
            *(const uint4*)(wlds + g*1024 + off);
      }
    }
    return;
  }
  if (bid < PREP_TX + PREP_W + PREP_WH) {    // ---- head weights [48][512] + bias
    const int t = (bid - PREP_TX - PREP_W)*256 + tid;
    const int n = t >> 9, c = t & 511;
    float v = 0.f;
    if (n < 9) v = cw[n*512 + c];
    else if (n < 45) v = rw[(n-9)*512 + c];
    wh[t] = f2bf(v);
    if (c == 0) {
      float bv = 0.f;
      if (n < 9) bv = cb[n];
      else if (n < 45) bv = rb[n-9];
      hb[n] = bv;
    }
    return;
  }
  if (bid < PREP_TX + PREP_W + PREP_WH + PREP_HALO) {  // ---- zero one halo cell
    const int q = bid - (PREP_TX + PREP_W + PREP_WH);
    const int b = q / 132, hc = q - b*132;
    int hh, ww;
    if (hc < 34)       { hh = 0;        ww = hc; }
    else if (hc < 68)  { hh = 33;       ww = hc - 34; }
    else if (hc < 100) { hh = hc - 67;  ww = 0; }
    else               { hh = hc - 99;  ww = 33; }
    uint4* dst = (uint4*)(xh + ((size_t)((b*34 + hh)*34 + ww))*2048);
    dst[tid] = make_uint4(0u, 0u, 0u, 0u);
    return;
  }
  if (bid < PREP_TX + PREP_W + PREP_WH + PREP_HALO + PREP_MAXG) {  // ---- maxg (b,g)
    const int p = bid - (PREP_TX + PREP_W + PREP_WH + PREP_HALO);
    const int b = p / NG, g = p - b*NG;
    const float4 gp = *(const float4*)(gtb + ((size_t)b*NG + g)*4);
    float m = 0.f;
#pragma unroll
    for (int j = 0; j < 36; ++j)
      m = fmaxf(m, iou_one(anc_of(tid + j*256), gp));
#pragma unroll
    for (int o = 32; o > 0; o >>= 1) m = fmaxf(m, __shfl_xor(m, o));
    if ((tid & 63) == 0) red[tid >> 6] = m;
    __syncthreads();
    if (tid == 0)
      maxg[b*NG + g] = __float_as_uint(fmaxf(fmaxf(red[0], red[1]), fmaxf(red[2], red[3])));
    return;
  }
  if (tid < 2) sums[tid] = 0.f;
  else if (tid == 2) *ctr = 0u;
}

// ---------------- conv 3x3 implicit GEMM, 256x256 tile, 8-phase schedule ----------------
__device__ __forceinline__ void wgbar() {
  asm volatile("" ::: "memory");
  __builtin_amdgcn_s_barrier();
  asm volatile("" ::: "memory");
}

__global__ __launch_bounds__(512, 2) void k_conv_gemm(const unsigned short* __restrict__ xh,
                                                      const unsigned short* __restrict__ wt,
                                                      unsigned short* __restrict__ hidp,
                                                      int csplit, int ksh) {
  // K-split half-tiles: A/B each [2 dbuf][2 ksub][256 rows][32 ch] bf16 = 64 KiB each
  __shared__ unsigned short As[2][2][256*32] __attribute__((aligned(16)));
  __shared__ unsigned short Bs[2][2][256*32] __attribute__((aligned(16)));
  const int t = threadIdx.x;
  const int L = blockIdx.x;
  const int kz = L & ((1 << ksh) - 1);          // split-K id in low bits -> per-XCD slice
  const int tile = L >> ksh;
  const int tileM = tile & 15, tileN = tile >> 4;
  const int o0 = tileN << 8;
  const int wv = t >> 6, lane = t & 63;
  const int wm = wv >> 2, wn = wv & 3;          // 2M x 4N waves, per-wave 128x64 out
  const int quad = lane >> 4, l16 = lane & 15;
  const int c_base = kz * csplit;
  const int tpg = csplit >> 6;                  // 64-ch K-tiles per tap
  const int tsh = 5 - ksh;                      // log2(tpg)
  const int NT = 9 * tpg;

  floatx4 acc[8][4];
#pragma unroll
  for (int mt = 0; mt < 8; ++mt)
#pragma unroll
    for (int nt = 0; nt < 4; ++nt)
      acc[mt][nt] = (floatx4){0.f, 0.f, 0.f, 0.f};

  // ---- staging geometry: one half-tile (256 rows x 32 ch) = 2 gload16/thread.
  // instr j covers rows [wv*32+j*16, +16); lane -> row lane>>2, seg slot lane&3.
  // slot s at row r holds logical seg q=(s-r)&3  => conflict-free 4-seg swizzle.
  const int lr4 = lane >> 2;
  const int sq = ((lane & 3) - lr4) & 3;        // logical seg for this lane's slot
  int gA[2], gB[2];
#pragma unroll
  for (int j = 0; j < 2; ++j) {
    const int r = wv*32 + j*16 + lr4;
    const int pix = tileM*256 + r;
    const int b = pix >> 10;
    const int hh = ((pix >> 5) & 31) + 1, ww = (pix & 31) + 1;
    gA[j] = ((b*34 + hh)*34 + ww)*2048 + c_base + sq*8;
    gB[j] = (o0 + r)*2048 + c_base + sq*8;
  }
  const int ldst0 = (wv*32)*32, ldst1 = (wv*32 + 16)*32;

  // stage half-tile: tau = K-tile index, part: 0=A_k0 1=B_k0 2=A_k1 3=B_k1
  auto stage = [&](int tau, int part) {
    if (tau >= NT) return;
    const int isB = part & 1, ks = part >> 1;
    const int sbuf = tau & 1;
    const int gs = tau >> tsh, cqs = tau & (tpg - 1);
    const int coff = cqs*64 + ks*32;
    if (!isB) {
      const int d = c_dsp[gs] + coff;
      gload16(xh + gA[0] + d, &As[sbuf][ks][ldst0]);
      gload16(xh + gA[1] + d, &As[sbuf][ks][ldst1]);
    } else {
      const size_t wo = (size_t)gs*NHID*NC + coff;
      gload16(wt + wo + gB[0], &Bs[sbuf][ks][ldst0]);
      gload16(wt + wo + gB[1], &Bs[sbuf][ks][ldst1]);
    }
  };

  // fragment read offsets (elements), swizzled seg; row == l16 (mod 4) everywhere
  const int ps = ((quad + l16) & 3) * 8;
  int aoff[8], boff[4];
#pragma unroll
  for (int mt = 0; mt < 8; ++mt) aoff[mt] = (wm*128 + mt*16 + l16)*32 + ps;
#pragma unroll
  for (int nt = 0; nt < 4; ++nt) boff[nt] = (wn*64 + nt*16 + l16)*32 + ps;

  // ---- prologue: stage k=0..5 (tile0 all, tile1 A_k0/B_k0), confirm k<=1
  stage(0, 0); stage(0, 1); stage(0, 2); stage(0, 3);
  stage(1, 0); stage(1, 1);
  VMCNT(8);
  wgbar();

#define MFMA16(MH) do { \
    __builtin_amdgcn_s_setprio(1); \
    _Pragma("unroll") \
    for (int mt = 0; mt < 4; ++mt) \
      _Pragma("unroll") \
      for (int nt = 0; nt < 4; ++nt) \
        acc[(MH)*4 + mt][nt] = __builtin_amdgcn_mfma_f32_16x16x32_bf16(af[mt], bw[nt], acc[(MH)*4 + mt][nt], 0, 0, 0); \
    __builtin_amdgcn_s_setprio(0); \
  } while (0)

  for (int kt = 0; kt < NT; ++kt) {
    const int buf = kt & 1;
    const unsigned short* A0 = &As[buf][0][0];
    const unsigned short* A1 = &As[buf][1][0];
    const unsigned short* B0 = &Bs[buf][0][0];
    const unsigned short* B1 = &Bs[buf][1][0];
    bf16x8 af[4], bw[4];

    // -- phase 0: ks=0, mh=0; stage A_k1(kt+1)
#pragma unroll
    for (int nt = 0; nt < 4; ++nt) bw[nt] = *(const bf16x8*)(B0 + boff[nt]);
#pragma unroll
    for (int mt = 0; mt < 4; ++mt) af[mt] = *(const bf16x8*)(A0 + aoff[mt]);
    stage(kt + 1, 2);
    wgbar();
    MFMA16(0);
    wgbar();

    // -- phase 1: ks=0, mh=1 (reuse bw); stage B_k1(kt+1); confirm tile kt A_k1/B_k1
#pragma unroll
    for (int mt = 0; mt < 4; ++mt) af[mt] = *(const bf16x8*)(A0 + aoff[4 + mt]);
    stage(kt + 1, 3);
    if (kt < NT - 1) { VMCNT(8); } else { VMCNT(0); }
    wgbar();
    MFMA16(1);
    wgbar();

    // -- phase 2: ks=1, mh=0; stage A_k0(kt+2)
#pragma unroll
    for (int nt = 0; nt < 4; ++nt) bw[nt] = *(const bf16x8*)(B1 + boff[nt]);
#pragma unroll
    for (int mt = 0; mt < 4; ++mt) af[mt] = *(const bf16x8*)(A1 + aoff[mt]);
    stage(kt + 2, 0);
    wgbar();
    MFMA16(0);
    wgbar();

    // -- phase 3: ks=1, mh=1; stage B_k0(kt+2); confirm tile kt+1 A_k0/B_k0
#pragma unroll
    for (int mt = 0; mt < 4; ++mt) af[mt] = *(const bf16x8*)(A1 + aoff[4 + mt]);
    stage(kt + 2, 1);
    if (kt < NT - 2) { VMCNT(8); }
    else if (kt == NT - 2) { VMCNT(4); }
    wgbar();
    MFMA16(1);
    wgbar();
  }
#undef MFMA16

  unsigned short* hp = hidp + (size_t)kz*NM*NHID;
  const int m0 = tileM*256 + wm*128;
  const int oc = o0 + wn*64;
#pragma unroll
  for (int mt = 0; mt < 8; ++mt) {
    const int m = m0 + mt*16 + quad*4;          // D: row = quad*4+reg
#pragma unroll
    for (int nt = 0; nt < 4; ++nt) {
      const int o = oc + nt*16 + l16;           // D: col = lane&15
#pragma unroll
      for (int r = 0; r < 4; ++r)
        hp[(size_t)(m + r)*NHID + o] = f2bf(acc[mt][nt][r]);
    }
  }
}

__device__ __forceinline__ float softplusf(float z) {
  return fmaxf(z, 0.f) + log1pf(expf(-fabsf(z)));
}
__device__ __forceinline__ float sl1f(float d) {
  const float ad = fabsf(d);
  return ad < 1.f ? 0.5f*d*d : ad - 0.5f;
}

// ---------------- heads GEMM (register fragments, no inner barriers) + assignment ----------------
__global__ __launch_bounds__(256) void k_heads_assign(const unsigned short* __restrict__ hidp,
                                                      const float* __restrict__ b1,
                                                      const unsigned short* __restrict__ wh,
                                                      const float* __restrict__ hb,
                                                      const float* __restrict__ gtb,
                                                      const unsigned int* __restrict__ maxg,
                                                      float* __restrict__ out,
                                                      float* __restrict__ sums,
                                                      unsigned int* __restrict__ ctr,
                                                      int nsplit) {
  __shared__ float red[4][16][48];
  __shared__ float hl[16][49];
  __shared__ float4 gt_s[20];
  __shared__ float  mg_s[20];
  const int t = threadIdx.x;
  const int bid = blockIdx.x;
  const int b = bid >> 6, pix0 = (bid & 63) << 4;

  if (t < 20) {
    gt_s[t] = *(const float4*)(gtb + ((size_t)b*NG + t)*4);
    mg_s[t] = __uint_as_float(maxg[b*NG + t]);
  }

  const int wv = t >> 6, lane = t & 63;
  const int quad = lane >> 4, l16 = lane & 15;
  floatx4 acc[3];
#pragma unroll
  for (int nt = 0; nt < 3; ++nt) acc[nt] = (floatx4){0.f, 0.f, 0.f, 0.f};

  const int m = bid*16 + l16;                 // A row (global hid row)
#pragma unroll
  for (int kk = 0; kk < 4; ++kk) {
    const int ch0 = wv*128 + kk*32 + quad*8;  // this lane's 8 channels
    float s[8] = {0.f,0.f,0.f,0.f,0.f,0.f,0.f,0.f};
    const size_t gi = (size_t)m*NHID + ch0;
    for (int sp = 0; sp < nsplit; ++sp) {
      const uint4 v = *(const uint4*)(hidp + (size_t)sp*NM*NHID + gi);
      s[0] += __uint_as_float(v.x << 16); s[1] += __uint_as_float(v.x & 0xffff0000u);
      s[2] += __uint_as_float(v.y << 16); s[3] += __uint_as_float(v.y & 0xffff0000u);
      s[4] += __uint_as_float(v.z << 16); s[5] += __uint_as_float(v.z & 0xffff0000u);
      s[6] += __uint_as_float(v.w << 16); s[7] += __uint_as_float(v.w & 0xffff0000u);
    }
    union { unsigned short u[8]; bf16x8 v; } af;
#pragma unroll
    for (int e = 0; e < 8; ++e)
      af.u[e] = f2bf(fmaxf(s[e] + b1[ch0 + e], 0.f));
#pragma unroll
    for (int nt = 0; nt < 3; ++nt) {
      const bf16x8 bf = *(const bf16x8*)(wh + (size_t)(nt*16 + l16)*NHID + ch0);
      acc[nt] = __builtin_amdgcn_mfma_f32_16x16x32_bf16(af.v, bf, acc[nt], 0, 0, 0);
    }
  }
  // cross-wave K reduce: D row = quad*4+r, col = l16 (per m89 layout)
#pragma unroll
  for (int nt = 0; nt < 3; ++nt)
#pragma unroll
    for (int r = 0; r < 4; ++r)
      red[wv][quad*4 + r][nt*16 + l16] = acc[nt][r];
  __syncthreads();
#pragma unroll
  for (int j = 0; j < 3; ++j) {
    const int idx = t + j*256;                // 768 = 16*48 entries
    const int i = idx / 48, c = idx - i*48;
    hl[i][c] = red[0][i][c] + red[1][i][c] + red[2][i][c] + red[3][i][c] + hb[c];
  }
  __syncthreads();

  // ---- assignment, losses, proposals for this block's 144 anchors ----
  float cs = 0.f, rs = 0.f;
  if (t < 144) {
    const int pixL = t / 9, a = t - pixL*9;
    const int pix = pix0 + pixL;
    const int n = pix*9 + a;
    const int idx = b*NANC + n;
    const Anc A = anc_of(n);

    float mx = -1.f; int gi = 0; bool pos = false;
    for (int g = 0; g < NG; ++g) {
      const float v = iou_one(A, gt_s[g]);    // bit-identical to prep-maxg
      const float mg = mg_s[g];
      pos = pos || (v > 0.7f) || ((v == mg) && (mg > 1e-8f));
      if (v > mx) { mx = v; gi = g; }
    }
    const bool neg = (mx < 0.3f) && !pos;
    const float posf = pos ? 1.f : 0.f;

    const float conf = hl[pixL][a];
    const float of0 = hl[pixL][9 + a*4 + 0];
    const float of1 = hl[pixL][9 + a*4 + 1];
    const float of2 = hl[pixL][9 + a*4 + 2];
    const float of3 = hl[pixL][9 + a*4 + 3];

    if (pos) cs = softplusf(-conf);
    else if (neg) cs = softplusf(conf);

    const float acx = (A.x1 + A.x2)*0.5f, acy = (A.y1 + A.y2)*0.5f;
    const float aw = A.x2 - A.x1, ah = A.y2 - A.y1;
    if (pos) {
      const float4 gp = gt_s[gi];
      const float gx1 = gp.x*0.03125f, gy1 = gp.y*0.03125f;
      const float gx2 = gp.z*0.03125f, gy2 = gp.w*0.03125f;
      const float gcx = (gx1+gx2)*0.5f, gcy = (gy1+gy2)*0.5f;
      const float gw = gx2-gx1, gh = gy2-gy1;
      const float t0 = (gcx-acx)/(aw+1e-8f), t1 = (gcy-acy)/(ah+1e-8f);
      const float t2 = logf((gw+1e-8f)/(aw+1e-8f)), t3 = logf((gh+1e-8f)/(ah+1e-8f));
      rs = sl1f(of0-t0) + sl1f(of1-t1) + sl1f(of2-t2) + sl1f(of3-t3);
    }

    const float pcx = acx + of0*aw, pcy = acy + of1*ah;
    const float pw = aw*expf(of2), ph = ah*expf(of3);
    float* op = out + 1 + (size_t)idx*4;
    op[0] = (pcx - pw*0.5f)*posf;
    op[1] = (pcy - ph*0.5f)*posf;
    op[2] = (pcx + pw*0.5f)*posf;
    op[3] = (pcy + ph*0.5f)*posf;
    out[1 + 4*(size_t)NB*NANC + idx] = posf;
  }
#pragma unroll
  for (int o = 32; o > 0; o >>= 1) { cs += __shfl_xor(cs, o); rs += __shfl_xor(rs, o); }
  if ((t & 63) == 0) { atomicAdd(&sums[0], cs); atomicAdd(&sums[1], rs); }

  __syncthreads();
  if (t == 0) {
    __threadfence();
    const unsigned int c = atomicAdd(ctr, 1u);
    if (c == 255u) {                          // 256 blocks total
      __threadfence();
      const float fcs = atomicAdd(&sums[0], 0.f);
      const float frs = atomicAdd(&sums[1], 0.f);
      out[0] = fcs*0.25f + 5.f*(frs*0.25f);   // w_conf*cls/B + w_reg*reg/B
    }
  }
}

extern "C" void kernel_launch(void* const* d_in, const int* in_sizes, int n_in,
                              void* d_out, int out_size, void* d_ws, size_t ws_size,
                              hipStream_t stream) {
  const float* x   = (const float*)d_in[0];
  const float* gtb = (const float*)d_in[1];
  // d_in[2] = gt_classes (unused by the loss)
  const float* w1  = (const float*)d_in[3];
  const float* b1  = (const float*)d_in[4];
  const float* cw  = (const float*)d_in[5];
  const float* cb  = (const float*)d_in[6];
  const float* rw  = (const float*)d_in[7];
  const float* rb  = (const float*)d_in[8];
  float* out = (float*)d_out;
  char* ws = (char*)d_ws;

  unsigned short* xh    = (unsigned short*)(ws + OFF_XH);
  unsigned short* wt    = (unsigned short*)(ws + OFF_WT);
  unsigned short* wh    = (unsigned short*)(ws + OFF_WH);
  float*          hb    = (float*)(ws + OFF_HB);
  unsigned int*   maxg  = (unsigned int*)(ws + OFF_MAXG);
  float*          sums  = (float*)(ws + OFF_SUMS);
  unsigned int*   ctr   = (unsigned int*)(ws + OFF_CTR);
  unsigned short* hidp  = (unsigned short*)(ws + OFF_HIDP);

  int nsplit = 8, ksh = 3;
  while (nsplit > 1 && OFF_HIDP + (size_t)nsplit*NM*NHID*2 > ws_size) { nsplit >>= 1; --ksh; }
  const int csplit = NC / nsplit;

  k_prep<<<PREP_NBLK, 256, 0, stream>>>(x, w1, cw, cb, rw, rb, gtb, xh, wt, wh, hb, maxg, sums, ctr);
  k_conv_gemm<<<32*nsplit, 512, 0, stream>>>(xh, wt, hidp, csplit, ksh);
  k_heads_assign<<<256, 256, 0, stream>>>(hidp, b1, wh, hb, gtb, maxg, out, sums, ctr, nsplit);
}

// Round 3
// 226.649 us; speedup vs baseline: 1.0452x; 1.0452x over previous
//
#include <hip/hip_runtime.h>

// RPN forward on gfx950. R13: k_conv_gemm = R10's proven loop structure
// (single-buffer LDS, __syncthreads, 0-conflict 8-slot seg swizzle, >=2 blocks/CU)
// with per-wave output grown 64x64 -> 128x64 (tile 256x128, acc[8][4]):
// LDS-read per MFMA drops 0.5KB -> 0.375KB (79 B/cyc demand < 112 B/cyc supply),
// removing R10's LDS-read plateau without touching the proven swizzle/overlap.
// R11 (coarse dbuf, 1 blk/CU) and R12 (half-K phases, 4-seg swizzle -> 7M bank
// conflicts) both regressed; their lessons: keep 128-B rows + 8-slot swizzle,
// keep fine-grain loop, keep 2+ blocks/CU. Accumulation order bit-identical.
// k_prep / k_heads unchanged.

typedef __bf16 bf16x8 __attribute__((ext_vector_type(8)));
typedef float floatx4 __attribute__((ext_vector_type(4)));

#define NB 4
#define NC 2048
#define NH 32
#define NW 32
#define NHID 512
#define NA 9
#define NG 20
#define NANC 9216
#define NM 4096

// workspace layout (bytes)
#define OFF_XH    0ull            // [4][34][34][2048] bf16 (zero halo) = 18939904
#define OFF_WT    18939904ull     // [9][512][2048]    bf16 = 18874368
#define OFF_WH    37814272ull     // [48][512]         bf16
#define OFF_HB    37863424ull     // [48] f32 (pad 256)
#define OFF_MAXG  37863680ull     // [4][20] uint (pad 512)
#define OFF_SUMS  37864192ull     // [2] f32 (pad 128)
#define OFF_CTR   37864320ull     // [1] uint (pad 128)
#define OFF_HIDP  37864448ull     // [nsplit][4096][512] bf16, 4194304 each

// k_prep block ranges
#define PREP_TX   4096
#define PREP_W    1024            // 512 o * 2 halves, LDS-staged
#define PREP_WH   96
#define PREP_HALO 528
#define PREP_MAXG 80
#define PREP_NBLK (PREP_TX + PREP_W + PREP_WH + PREP_HALO + PREP_MAXG + 1)

__device__ __forceinline__ unsigned short f2bf(float f) {
  unsigned int u = __float_as_uint(f);
  u = (u + 0x7fffu + ((u >> 16) & 1u)) >> 16;   // RNE
  return (unsigned short)u;
}

__device__ __forceinline__ void gload16(const void* g, void* l) {
  __builtin_amdgcn_global_load_lds(
      (const __attribute__((address_space(1))) unsigned int*)g,
      (__attribute__((address_space(3))) unsigned int*)l, 16, 0, 0);
}

__constant__ float c_aw[9] = {2.f,2.f,2.f,4.f,4.f,4.f,6.f,6.f,6.f};
__constant__ float c_ah[9] = {1.f,2.f,3.f,2.f,4.f,6.f,3.f,6.f,9.f};
// tap displacement in xh elements: ((g/3-1)*34 + (g%3-1)) * 2048
__constant__ int c_dsp[9] = {-71680, -69632, -67584, -2048, 0, 2048, 67584, 69632, 71680};

// ---- strict-f32 anchor/IoU helpers (bit-identical in prep-maxg + assign) ----
struct Anc { float x1, y1, x2, y2, areaA; };
__device__ __forceinline__ Anc anc_of(int n) {
  const int a = n % 9, pix = n / 9;
  const int xi = pix & 31, yi = pix >> 5;
  const float hw = c_aw[a]*0.5f, hh = c_ah[a]*0.5f;
  const float xc = xi + 0.5f, yc = yi + 0.5f;
  Anc A;
  A.x1 = fminf(fmaxf(xc - hw, 0.f), 32.f);
  A.y1 = fminf(fmaxf(yc - hh, 0.f), 32.f);
  A.x2 = fminf(fmaxf(xc + hw, 0.f), 32.f);
  A.y2 = fminf(fmaxf(yc + hh, 0.f), 32.f);
  A.areaA = __fmul_rn(__fsub_rn(A.x2, A.x1), __fsub_rn(A.y2, A.y1));
  return A;
}
__device__ __forceinline__ float iou_one(const Anc& A, float4 gp) {
  const float gx1 = gp.x * 0.03125f, gy1 = gp.y * 0.03125f;   // /32 exact
  const float gx2 = gp.z * 0.03125f, gy2 = gp.w * 0.03125f;
  const float dx = fmaxf(__fsub_rn(fminf(A.x2, gx2), fmaxf(A.x1, gx1)), 0.f);
  const float dy = fmaxf(__fsub_rn(fminf(A.y2, gy2), fmaxf(A.y1, gy1)), 0.f);
  const float inter = __fmul_rn(dx, dy);
  const float areaG = __fmul_rn(__fsub_rn(gx2, gx1), __fsub_rn(gy2, gy1));
  const float den = __fadd_rn(__fsub_rn(__fadd_rn(A.areaA, areaG), inter), 1e-8f);
  return __fdiv_rn(inter, den);
}

// ---------------- fused prep ----------------
__global__ __launch_bounds__(256) void k_prep(const float* __restrict__ x,
                                              const float* __restrict__ w1,
                                              const float* __restrict__ cw, const float* __restrict__ cb,
                                              const float* __restrict__ rw, const float* __restrict__ rb,
                                              const float* __restrict__ gtb,
                                              unsigned short* __restrict__ xh,
                                              unsigned short* __restrict__ wt,
                                              unsigned short* __restrict__ wh, float* __restrict__ hb,
                                              unsigned int* __restrict__ maxg,
                                              float* __restrict__ sums, unsigned int* __restrict__ ctr) {
  __shared__ float tile[64][33];
  __shared__ unsigned short wlds[9*1024];
  __shared__ float red[4];
  const int bid = blockIdx.x;
  const int tid = threadIdx.x;

  if (bid < PREP_TX) {                       // ---- x: NCHW f32 -> halo NHWC bf16
    const int c0 = (bid & 31) << 6;
    const int h  = (bid >> 5) & 31;
    const int b  = bid >> 10;
    const int w = tid & 31, cl = tid >> 5;
    const float* src = x + (((size_t)b*NC + c0)*NH + h)*NW;
#pragma unroll
    for (int j = 0; j < 8; ++j) {
      const int c = cl + j*8;
      tile[c][w] = src[(size_t)c*NH*NW + w];
    }
    __syncthreads();
    unsigned short* dst = xh + ((size_t)(b*34 + h + 1)*34 + 1)*2048 + c0;
    const int w2 = tid >> 3, c8 = (tid & 7) << 3;   // 16B store per lane
    unsigned int pk[4];
#pragma unroll
    for (int k = 0; k < 4; ++k) {
      const unsigned int lo = f2bf(tile[c8 + 2*k][w2]);
      const unsigned int hi = f2bf(tile[c8 + 2*k + 1][w2]);
      pk[k] = lo | (hi << 16);
    }
    *(uint4*)(dst + (size_t)w2*2048 + c8) = make_uint4(pk[0], pk[1], pk[2], pk[3]);
    return;
  }
  if (bid < PREP_TX + PREP_W) {              // ---- w1 -> [g][O][C] bf16, LDS-staged
    const int p = bid - PREP_TX;
    const int o = p >> 1, half = p & 1;
    const int c_base = half << 10;
    const float* src = w1 + ((size_t)(o*2048 + c_base))*9;   // 9216 contiguous floats
#pragma unroll
    for (int j = 0; j < 9; ++j) {            // read float4, scatter bf16 into [g][c] LDS
      const int f0 = (j*256 + tid)*4;
      const float4 v = *(const float4*)(src + f0);
      const float vv[4] = {v.x, v.y, v.z, v.w};
#pragma unroll
      for (int e = 0; e < 4; ++e) {
        const int f = f0 + e;
        const int c = f/9, g = f - c*9;
        wlds[g*1024 + c] = f2bf(vv[e]);
      }
    }
    __syncthreads();
#pragma unroll
    for (int j = 0; j < 5; ++j) {            // 1152 uint4 writes (9 g * 128)
      const int idx = j*256 + tid;
      if (idx < 1152) {
        const int g = idx >> 7, off = (idx & 127) << 3;
        *(uint4*)(wt + (size_t)g*NHID*NC + o*2048 + c_base + off) =
            *(const uint4*)(wlds + g*1024 + off);
      }
    }
    return;
  }
  if (bid < PREP_TX + PREP_W + PREP_WH) {    // ---- head weights [48][512] + bias
    const int t = (bid - PREP_TX - PREP_W)*256 + tid;
    const int n = t >> 9, c = t & 511;
    float v = 0.f;
    if (n < 9) v = cw[n*512 + c];
    else if (n < 45) v = rw[(n-9)*512 + c];
    wh[t] = f2bf(v);
    if (c == 0) {
      float bv = 0.f;
      if (n < 9) bv = cb[n];
      else if (n < 45) bv = rb[n-9];
      hb[n] = bv;
    }
    return;
  }
  if (bid < PREP_TX + PREP_W + PREP_WH + PREP_HALO) {  // ---- zero one halo cell
    const int q = bid - (PREP_TX + PREP_W + PREP_WH);
    const int b = q / 132, hc = q - b*132;
    int hh, ww;
    if (hc < 34)       { hh = 0;        ww = hc; }
    else if (hc < 68)  { hh = 33;       ww = hc - 34; }
    else if (hc < 100) { hh = hc - 67;  ww = 0; }
    else               { hh = hc - 99;  ww = 33; }
    uint4* dst = (uint4*)(xh + ((size_t)((b*34 + hh)*34 + ww))*2048);
    dst[tid] = make_uint4(0u, 0u, 0u, 0u);
    return;
  }
  if (bid < PREP_TX + PREP_W + PREP_WH + PREP_HALO + PREP_MAXG) {  // ---- maxg (b,g)
    const int p = bid - (PREP_TX + PREP_W + PREP_WH + PREP_HALO);
    const int b = p / NG, g = p - b*NG;
    const float4 gp = *(const float4*)(gtb + ((size_t)b*NG + g)*4);
    float m = 0.f;
#pragma unroll
    for (int j = 0; j < 36; ++j)
      m = fmaxf(m, iou_one(anc_of(tid + j*256), gp));
#pragma unroll
    for (int o = 32; o > 0; o >>= 1) m = fmaxf(m, __shfl_xor(m, o));
    if ((tid & 63) == 0) red[tid >> 6] = m;
    __syncthreads();
    if (tid == 0)
      maxg[b*NG + g] = __float_as_uint(fmaxf(fmaxf(red[0], red[1]), fmaxf(red[2], red[3])));
    return;
  }
  if (tid < 2) sums[tid] = 0.f;
  else if (tid == 2) *ctr = 0u;
}

// ---------------- conv 3x3 implicit GEMM, 256x128 tile, per-wave 128x64 ----------------
__global__ __launch_bounds__(256, 2) void k_conv_gemm(const unsigned short* __restrict__ xh,
                                                      const unsigned short* __restrict__ wt,
                                                      unsigned short* __restrict__ hidp,
                                                      int csplit, int ksh) {
  __shared__ unsigned short As[256*64] __attribute__((aligned(16)));   // 32 KiB
  __shared__ unsigned short Bs[128*64] __attribute__((aligned(16)));   // 16 KiB
  const int t = threadIdx.x;
  const int L = blockIdx.x;
  const int kz = L & ((1 << ksh) - 1);          // split-K id in low bits -> per-XCD slice
  const int tile = L >> ksh;
  const int tileM = tile & 15, tileN = tile >> 4;   // 16 M-tiles x 4 N-tiles
  const int o0 = tileN << 7;
  const int wv = t >> 6, lane = t & 63;
  const int wm = wv >> 1, wn = wv & 1;          // 2M x 2N waves, per-wave 128x64 out
  const int quad = lane >> 4, l16 = lane & 15;
  const int c_base = kz * csplit;

  floatx4 acc[8][4];
#pragma unroll
  for (int mt = 0; mt < 8; ++mt)
#pragma unroll
    for (int nt = 0; nt < 4; ++nt)
      acc[mt][nt] = (floatx4){0.f, 0.f, 0.f, 0.f};

  // staging: instr j covers 32 LDS rows (8 rows/wave); lane -> row lr, slot pos.
  // slot pos at row r holds logical seg (pos - r)&7  => 0-conflict swizzle (measured R10)
  const int lr = lane >> 3, pos = lane & 7;
  int gA[8], gB[4];
#pragma unroll
  for (int j = 0; j < 8; ++j) {
    const int row = j*32 + wv*8 + lr;
    const int sd = (pos - row) & 7;
    const int pix = tileM*256 + row;            // 256 rows = 8 h-rows of one image
    const int b = pix >> 10;
    const int hh = ((pix >> 5) & 31) + 1, ww = (pix & 31) + 1;
    gA[j] = ((b*34 + hh)*34 + ww)*2048 + c_base + sd*8;
  }
#pragma unroll
  for (int j = 0; j < 4; ++j) {
    const int row = j*32 + wv*8 + lr;
    const int sd = (pos - row) & 7;
    gB[j] = (o0 + row)*2048 + c_base + sd*8;
  }

  for (int g = 0; g < 9; ++g) {
    const int dsp = c_dsp[g];
    const unsigned short* wgp = wt + (size_t)g*NHID*NC;
    for (int c0 = 0; c0 < csplit; c0 += 64) {
#pragma unroll
      for (int j = 0; j < 8; ++j)
        gload16(xh + gA[j] + dsp + c0, As + (j*32 + wv*8)*64);
#pragma unroll
      for (int j = 0; j < 4; ++j)
        gload16(wgp + gB[j] + c0, Bs + (j*32 + wv*8)*64);
      __syncthreads();
#pragma unroll
      for (int sub = 0; sub < 2; ++sub) {
        const int ps = ((sub*4 + quad) + l16) & 7;   // row == l16 (mod 8) everywhere
        bf16x8 af[8], bw[4];
#pragma unroll
        for (int mt = 0; mt < 8; ++mt)
          af[mt] = *(const bf16x8*)(As + (wm*128 + mt*16 + l16)*64 + ps*8);
#pragma unroll
        for (int nt = 0; nt < 4; ++nt)
          bw[nt] = *(const bf16x8*)(Bs + (wn*64 + nt*16 + l16)*64 + ps*8);
#pragma unroll
        for (int mt = 0; mt < 8; ++mt)
#pragma unroll
          for (int nt = 0; nt < 4; ++nt)
            acc[mt][nt] = __builtin_amdgcn_mfma_f32_16x16x32_bf16(af[mt], bw[nt], acc[mt][nt], 0, 0, 0);
      }
      __syncthreads();
    }
  }

  unsigned short* hp = hidp + (size_t)kz*NM*NHID;
  const int m0 = tileM*256 + wm*128;
  const int oc = o0 + wn*64;
#pragma unroll
  for (int mt = 0; mt < 8; ++mt) {
    const int m = m0 + mt*16 + quad*4;          // D: row = quad*4+reg
#pragma unroll
    for (int nt = 0; nt < 4; ++nt) {
      const int o = oc + nt*16 + l16;           // D: col = lane&15
#pragma unroll
      for (int r = 0; r < 4; ++r)
        hp[(size_t)(m + r)*NHID + o] = f2bf(acc[mt][nt][r]);
    }
  }
}

__device__ __forceinline__ float softplusf(float z) {
  return fmaxf(z, 0.f) + log1pf(expf(-fabsf(z)));
}
__device__ __forceinline__ float sl1f(float d) {
  const float ad = fabsf(d);
  return ad < 1.f ? 0.5f*d*d : ad - 0.5f;
}

// ---------------- heads GEMM (register fragments, no inner barriers) + assignment ----------------
__global__ __launch_bounds__(256) void k_heads_assign(const unsigned short* __restrict__ hidp,
                                                      const float* __restrict__ b1,
                                                      const unsigned short* __restrict__ wh,
                                                      const float* __restrict__ hb,
                                                      const float* __restrict__ gtb,
                                                      const unsigned int* __restrict__ maxg,
                                                      float* __restrict__ out,
                                                      float* __restrict__ sums,
                                                      unsigned int* __restrict__ ctr,
                                                      int nsplit) {
  __shared__ float red[4][16][48];
  __shared__ float hl[16][49];
  __shared__ float4 gt_s[20];
  __shared__ float  mg_s[20];
  const int t = threadIdx.x;
  const int bid = blockIdx.x;
  const int b = bid >> 6, pix0 = (bid & 63) << 4;

  if (t < 20) {
    gt_s[t] = *(const float4*)(gtb + ((size_t)b*NG + t)*4);
    mg_s[t] = __uint_as_float(maxg[b*NG + t]);
  }

  const int wv = t >> 6, lane = t & 63;
  const int quad = lane >> 4, l16 = lane & 15;
  floatx4 acc[3];
#pragma unroll
  for (int nt = 0; nt < 3; ++nt) acc[nt] = (floatx4){0.f, 0.f, 0.f, 0.f};

  const int m = bid*16 + l16;                 // A row (global hid row)
#pragma unroll
  for (int kk = 0; kk < 4; ++kk) {
    const int ch0 = wv*128 + kk*32 + quad*8;  // this lane's 8 channels
    float s[8] = {0.f,0.f,0.f,0.f,0.f,0.f,0.f,0.f};
    const size_t gi = (size_t)m*NHID + ch0;
    for (int sp = 0; sp < nsplit; ++sp) {
      const uint4 v = *(const uint4*)(hidp + (size_t)sp*NM*NHID + gi);
      s[0] += __uint_as_float(v.x << 16); s[1] += __uint_as_float(v.x & 0xffff0000u);
      s[2] += __uint_as_float(v.y << 16); s[3] += __uint_as_float(v.y & 0xffff0000u);
      s[4] += __uint_as_float(v.z << 16); s[5] += __uint_as_float(v.z & 0xffff0000u);
      s[6] += __uint_as_float(v.w << 16); s[7] += __uint_as_float(v.w & 0xffff0000u);
    }
    union { unsigned short u[8]; bf16x8 v; } af;
#pragma unroll
    for (int e = 0; e < 8; ++e)
      af.u[e] = f2bf(fmaxf(s[e] + b1[ch0 + e], 0.f));
#pragma unroll
    for (int nt = 0; nt < 3; ++nt) {
      const bf16x8 bf = *(const bf16x8*)(wh + (size_t)(nt*16 + l16)*NHID + ch0);
      acc[nt] = __builtin_amdgcn_mfma_f32_16x16x32_bf16(af.v, bf, acc[nt], 0, 0, 0);
    }
  }
  // cross-wave K reduce: D row = quad*4+r, col = l16 (per m89 layout)
#pragma unroll
  for (int nt = 0; nt < 3; ++nt)
#pragma unroll
    for (int r = 0; r < 4; ++r)
      red[wv][quad*4 + r][nt*16 + l16] = acc[nt][r];
  __syncthreads();
#pragma unroll
  for (int j = 0; j < 3; ++j) {
    const int idx = t + j*256;                // 768 = 16*48 entries
    const int i = idx / 48, c = idx - i*48;
    hl[i][c] = red[0][i][c] + red[1][i][c] + red[2][i][c] + red[3][i][c] + hb[c];
  }
  __syncthreads();

  // ---- assignment, losses, proposals for this block's 144 anchors ----
  float cs = 0.f, rs = 0.f;
  if (t < 144) {
    const int pixL = t / 9, a = t - pixL*9;
    const int pix = pix0 + pixL;
    const int n = pix*9 + a;
    const int idx = b*NANC + n;
    const Anc A = anc_of(n);

    float mx = -1.f; int gi = 0; bool pos = false;
    for (int g = 0; g < NG; ++g) {
      const float v = iou_one(A, gt_s[g]);    // bit-identical to prep-maxg
      const float mg = mg_s[g];
      pos = pos || (v > 0.7f) || ((v == mg) && (mg > 1e-8f));
      if (v > mx) { mx = v; gi = g; }
    }
    const bool neg = (mx < 0.3f) && !pos;
    const float posf = pos ? 1.f : 0.f;

    const float conf = hl[pixL][a];
    const float of0 = hl[pixL][9 + a*4 + 0];
    const float of1 = hl[pixL][9 + a*4 + 1];
    const float of2 = hl[pixL][9 + a*4 + 2];
    const float of3 = hl[pixL][9 + a*4 + 3];

    if (pos) cs = softplusf(-conf);
    else if (neg) cs = softplusf(conf);

    const float acx = (A.x1 + A.x2)*0.5f, acy = (A.y1 + A.y2)*0.5f;
    const float aw = A.x2 - A.x1, ah = A.y2 - A.y1;
    if (pos) {
      const float4 gp = gt_s[gi];
      const float gx1 = gp.x*0.03125f, gy1 = gp.y*0.03125f;
      const float gx2 = gp.z*0.03125f, gy2 = gp.w*0.03125f;
      const float gcx = (gx1+gx2)*0.5f, gcy = (gy1+gy2)*0.5f;
      const float gw = gx2-gx1, gh = gy2-gy1;
      const float t0 = (gcx-acx)/(aw+1e-8f), t1 = (gcy-acy)/(ah+1e-8f);
      const float t2 = logf((gw+1e-8f)/(aw+1e-8f)), t3 = logf((gh+1e-8f)/(ah+1e-8f));
      rs = sl1f(of0-t0) + sl1f(of1-t1) + sl1f(of2-t2) + sl1f(of3-t3);
    }

    const float pcx = acx + of0*aw, pcy = acy + of1*ah;
    const float pw = aw*expf(of2), ph = ah*expf(of3);
    float* op = out + 1 + (size_t)idx*4;
    op[0] = (pcx - pw*0.5f)*posf;
    op[1] = (pcy - ph*0.5f)*posf;
    op[2] = (pcx + pw*0.5f)*posf;
    op[3] = (pcy + ph*0.5f)*posf;
    out[1 + 4*(size_t)NB*NANC + idx] = posf;
  }
#pragma unroll
  for (int o = 32; o > 0; o >>= 1) { cs += __shfl_xor(cs, o); rs += __shfl_xor(rs, o); }
  if ((t & 63) == 0) { atomicAdd(&sums[0], cs); atomicAdd(&sums[1], rs); }

  __syncthreads();
  if (t == 0) {
    __threadfence();
    const unsigned int c = atomicAdd(ctr, 1u);
    if (c == 255u) {                          // 256 blocks total
      __threadfence();
      const float fcs = atomicAdd(&sums[0], 0.f);
      const float frs = atomicAdd(&sums[1], 0.f);
      out[0] = fcs*0.25f + 5.f*(frs*0.25f);   // w_conf*cls/B + w_reg*reg/B
    }
  }
}

extern "C" void kernel_launch(void* const* d_in, const int* in_sizes, int n_in,
                              void* d_out, int out_size, void* d_ws, size_t ws_size,
                              hipStream_t stream) {
  const float* x   = (const float*)d_in[0];
  const float* gtb = (const float*)d_in[1];
  // d_in[2] = gt_classes (unused by the loss)
  const float* w1  = (const float*)d_in[3];
  const float* b1  = (const float*)d_in[4];
  const float* cw  = (const float*)d_in[5];
  const float* cb  = (const float*)d_in[6];
  const float* rw  = (const float*)d_in[7];
  const float* rb  = (const float*)d_in[8];
  float* out = (float*)d_out;
  char* ws = (char*)d_ws;

  unsigned short* xh    = (unsigned short*)(ws + OFF_XH);
  unsigned short* wt    = (unsigned short*)(ws + OFF_WT);
  unsigned short* wh    = (unsigned short*)(ws + OFF_WH);
  float*          hb    = (float*)(ws + OFF_HB);
  unsigned int*   maxg  = (unsigned int*)(ws + OFF_MAXG);
  float*          sums  = (float*)(ws + OFF_SUMS);
  unsigned int*   ctr   = (unsigned int*)(ws + OFF_CTR);
  unsigned short* hidp  = (unsigned short*)(ws + OFF_HIDP);

  int nsplit = 8, ksh = 3;
  while (nsplit > 1 && OFF_HIDP + (size_t)nsplit*NM*NHID*2 > ws_size) { nsplit >>= 1; --ksh; }
  const int csplit = NC / nsplit;

  k_prep<<<PREP_NBLK, 256, 0, stream>>>(x, w1, cw, cb, rw, rb, gtb, xh, wt, wh, hb, maxg, sums, ctr);
  k_conv_gemm<<<64*nsplit, 256, 0, stream>>>(xh, wt, hidp, csplit, ksh);
  k_heads_assign<<<256, 256, 0, stream>>>(hidp, b1, wh, hb, gtb, maxg, out, sums, ctr, nsplit);
}